// Round 13
// baseline (151.615 us; speedup 1.0000x reference)
//
#include <hip/hip_runtime.h>
#include <hip/hip_bf16.h>

#define DFEAT 64
#define SBSHIFT 9            // 512 rows per superbucket
#define SBROWS 512
#define CAPSHIFT 13          // 8192 edge slots per superbucket region
#define CAP 8192
#define CHUNK 2048           // R25: edges per binA block (4096 R20-good; 8192 regressed)
#define RPT 8                // CHUNK/256
#define CURPAD 16            // sbcursor padded: one counter per 64B line

typedef __attribute__((ext_vector_type(8))) unsigned short ushort8;
typedef __attribute__((ext_vector_type(8))) short short8;    // MFMA A/B frag (8 bf16)
typedef __attribute__((ext_vector_type(4))) float f32x4;     // MFMA C/D frag

static __device__ __forceinline__ unsigned short f2bf(float f) {
    __hip_bfloat16 h = __float2bfloat16(f);   // RNE
    unsigned short u;
    __builtin_memcpy(&u, &h, 2);
    return u;
}

// ---------------------------------------------------------------------------
// R25: CHUNK 4096->2048. R24 (8192) REGRESSED binA_xw 33->43.7us and proved
// binA is per-block LATENCY-CHAIN-bound, not cursor-contention-bound
// (halving contention hurt). So invert: 611 shorter blocks (8-iteration
// passes), 2.4 binA blocks/CU interleaved into the xw sea => better latency
// hiding; cursor RMWs double, which R24 showed is not the limiter.
// [R20: MFMA xw kept. R17: spmm x2 unroll kept. R21/R23: rowmap closed.
//  R15/R16: no grid-barrier fusion on MI355X.]
// ---------------------------------------------------------------------------

// ---------------------------------------------------------------------------
// 1) FUSED: binA (blocks [0,binABlocks)) || xw-MFMA (64 rows/block).
//    LDS: binA 2 KB (hist+cur); xw uses none.
// ---------------------------------------------------------------------------
__global__ __launch_bounds__(256) void binA_xw_kernel(
        const float* __restrict__ feat, const float* __restrict__ W,
        unsigned short* __restrict__ Yu, int n,
        const int* __restrict__ ei, int E,
        int* __restrict__ sbcursor, int* __restrict__ packed, int binABlocks) {
    __shared__ int hist[256];
    __shared__ int cur[256];

    if (blockIdx.x < binABlocks) {
        // ---------------- binA part ----------------
        int t = threadIdx.x;
        hist[t] = 0;
        __syncthreads();

        int base = blockIdx.x * CHUNK;
        int rv[RPT];
#pragma unroll
        for (int k = 0; k < RPT; k++) {
            int idx = base + k * 256 + t;
            rv[k] = (idx < E) ? ei[idx] : -1;
            if (rv[k] >= 0) atomicAdd(&hist[rv[k] >> SBSHIFT], 1);
        }
        __syncthreads();

        int h = hist[t];
        cur[t] = (h > 0) ? atomicAdd(&sbcursor[t * CURPAD], h) : 0;  // absolute base
        __syncthreads();

#pragma unroll
        for (int k = 0; k < RPT; k++) {
            int idx = base + k * 256 + t;
            if (rv[k] >= 0) {
                int r = rv[k];
                int c = ei[E + idx];
                int sb = r >> SBSHIFT;
                int pos = atomicAdd(&cur[sb], 1);
                if (pos < CAP)
                    packed[(sb << CAPSHIFT) + pos] = ((r & (SBROWS - 1)) << 17) | c;
            }
        }
    } else {
        // ---------------- xw part: MFMA, 16 rows/wave, 64 rows/block -------
        int bid  = blockIdx.x - binABlocks;
        int wave = threadIdx.x >> 6;
        int lane = threadIdx.x & 63;
        int lr = lane & 15;           // A-row / B-col / C-col within tile
        int lg = lane >> 4;           // k-group (A,B) / row-group (C)
        int R0 = bid * 64 + wave * 16;

        // B fragments: W[64][64] row-major; b[nb][ks][j] = W[ks*32+lg*8+j][nb*16+lr]
        short8 bf[4][2];
#pragma unroll
        for (int nb = 0; nb < 4; nb++) {
#pragma unroll
            for (int ks = 0; ks < 2; ks++) {
#pragma unroll
                for (int j = 0; j < 8; j++) {
                    int k = ks * 32 + lg * 8 + j;
                    bf[nb][ks][j] = (short)f2bf(W[k * DFEAT + nb * 16 + lr]);
                }
            }
        }

        // A fragments: a[ks][j] = feat[R0+lr][ks*32+lg*8+j]
        short8 af[2];
        int arow = R0 + lr;
        if (arow < n) {
            const float4* ap =
                (const float4*)(feat + (size_t)arow * DFEAT + lg * 8);
            float4 f0 = ap[0];            // k = lg*8 .. +3      (ks=0)
            float4 f1 = ap[1];            // k = lg*8+4 .. +7    (ks=0)
            float4 f2 = ap[8];            // +32 floats = 8 float4 (ks=1)
            float4 f3 = ap[9];
            af[0][0] = (short)f2bf(f0.x); af[0][1] = (short)f2bf(f0.y);
            af[0][2] = (short)f2bf(f0.z); af[0][3] = (short)f2bf(f0.w);
            af[0][4] = (short)f2bf(f1.x); af[0][5] = (short)f2bf(f1.y);
            af[0][6] = (short)f2bf(f1.z); af[0][7] = (short)f2bf(f1.w);
            af[1][0] = (short)f2bf(f2.x); af[1][1] = (short)f2bf(f2.y);
            af[1][2] = (short)f2bf(f2.z); af[1][3] = (short)f2bf(f2.w);
            af[1][4] = (short)f2bf(f3.x); af[1][5] = (short)f2bf(f3.y);
            af[1][6] = (short)f2bf(f3.z); af[1][7] = (short)f2bf(f3.w);
        } else {
#pragma unroll
            for (int j = 0; j < 8; j++) { af[0][j] = 0; af[1][j] = 0; }
        }

        // C[16x16] per N-tile: accumulate the two K-steps
        f32x4 c[4];
#pragma unroll
        for (int nb = 0; nb < 4; nb++) {
            c[nb] = (f32x4){0.f, 0.f, 0.f, 0.f};
            c[nb] = __builtin_amdgcn_mfma_f32_16x16x32_bf16(af[0], bf[nb][0],
                                                            c[nb], 0, 0, 0);
            c[nb] = __builtin_amdgcn_mfma_f32_16x16x32_bf16(af[1], bf[nb][1],
                                                            c[nb], 0, 0, 0);
        }

        // store: c[nb][i] -> Y[R0 + lg*4 + i][nb*16 + lr] (bf16)
#pragma unroll
        for (int i = 0; i < 4; i++) {
            int row = R0 + lg * 4 + i;
            if (row < n) {
#pragma unroll
                for (int nb = 0; nb < 4; nb++)
                    Yu[(size_t)row * DFEAT + nb * 16 + lr] = f2bf(c[nb][i]);
            }
        }
    }
}

// ---------------------------------------------------------------------------
// 2) binB: per-superbucket counting sort into CSR order (block-private dense
//    region, native int LDS atomics only). Emits row_beg/row_end/dis.
// ---------------------------------------------------------------------------
__global__ void binB_kernel(const int* __restrict__ sbcursor, const int* __restrict__ packed,
                            int* __restrict__ csr_col, int* __restrict__ row_beg,
                            int* __restrict__ row_end, float* __restrict__ dis, int n) {
    __shared__ int rcnt[SBROWS];
    __shared__ int rcur[SBROWS];
    int sb = blockIdx.x;
    int t = threadIdx.x;
    int cnt = min(sbcursor[sb * CURPAD], CAP);
    const int* pk = packed + ((size_t)sb << CAPSHIFT);
    for (int i = t; i < SBROWS; i += 256) rcnt[i] = 0;
    __syncthreads();
    for (int i = t; i < cnt; i += 256) atomicAdd(&rcnt[pk[i] >> 17], 1);
    __syncthreads();
    // exclusive scan of rcnt[512] by wave 0 (8 elems/lane + shfl_up scan)
    if (t < 64) {
        int v[8];
        int run = 0;
#pragma unroll
        for (int k = 0; k < 8; k++) { v[k] = run; run += rcnt[t * 8 + k]; }
        int x = run;
        for (int off = 1; off < 64; off <<= 1) {
            int y = __shfl_up(x, off);
            if (t >= off) x += y;
        }
        int excl = x - run;
#pragma unroll
        for (int k = 0; k < 8; k++) rcur[t * 8 + k] = excl + v[k];
    }
    __syncthreads();
    int rows = min(SBROWS, n - sb * SBROWS);
    for (int rl = t; rl < rows; rl += 256) {
        int beg = (sb << CAPSHIFT) + rcur[rl];
        int d = rcnt[rl];
        int r = sb * SBROWS + rl;
        row_beg[r] = beg;
        row_end[r] = beg + d;
        dis[r] = (d > 0) ? rsqrtf((float)d) : 0.0f;
    }
    __syncthreads();
    for (int i = t; i < cnt; i += 256) {
        int p = pk[i];
        int pos = atomicAdd(&rcur[p >> 17], 1);
        csr_col[(sb << CAPSHIFT) + pos] = p & 0x1FFFF;
    }
}

// ---------------------------------------------------------------------------
// 3) spmm: FOUR rows per wave (one per 16-lane quarter). Quarter layout:
//    2 edge slots (sub) x 8 feat chunks (f8, 16 B bf16 loads). Guard-free
//    inner loop (tail slots shfl from lanes holding c=0/dv=0 -> Y[0]
//    broadcast gather, fma adds 0). x2 unroll (R17 measured-best; x4 was
//    neutral). Register accumulate, quarter-local shfl_xor reduce, fused
//    dis/bias/relu epilogue. Zero atomics.
// ---------------------------------------------------------------------------
__global__ __launch_bounds__(256) void spmm_kernel(
        const int* __restrict__ row_beg, const int* __restrict__ row_end,
        const int* __restrict__ csr_col, const float* __restrict__ dis,
        const ushort8* __restrict__ Y, const float* __restrict__ bias,
        float* __restrict__ out, int n) {
    int wid = (int)(((long long)blockIdx.x * blockDim.x + threadIdx.x) >> 6);
    int lane = threadIdx.x & 63;
    int h = lane >> 4;            // which of the wave's four rows (0..3)
    int lq = lane & 15;           // lane within quarter
    int qb = h << 4;              // quarter base lane
    int row = wid * 4 + h;
    bool active = row < n;
    int s = active ? row_beg[row] : 0;
    int e = active ? row_end[row] : 0;
    int sub = lq >> 3;            // edge slot 0..1
    int f8 = lane & 7;            // feat chunk 0..7
    float acc[8] = {0.f, 0.f, 0.f, 0.f, 0.f, 0.f, 0.f, 0.f};
    for (int base = s; base < e; base += 16) {
        int cnt = min(16, e - base);
        int c = 0;
        float dv = 0.f;
        if (lq < cnt) { c = csr_col[base + lq]; dv = dis[c]; }
        for (int i = 0; i < cnt; i += 4) {
            int   ce0 = __shfl(c,  qb + i + sub);      // tail slot -> c=0
            float de0 = __shfl(dv, qb + i + sub);      // -> 0.0f
            int   ce1 = __shfl(c,  qb + i + 2 + sub);
            float de1 = __shfl(dv, qb + i + 2 + sub);
            ushort8 y0 = Y[(size_t)ce0 * 8 + f8];      // two gathers in flight
            ushort8 y1 = Y[(size_t)ce1 * 8 + f8];
#pragma unroll
            for (int k = 0; k < 8; k++)
                acc[k] = fmaf(de0, __uint_as_float(((unsigned)y0[k]) << 16), acc[k]);
#pragma unroll
            for (int k = 0; k < 8; k++)
                acc[k] = fmaf(de1, __uint_as_float(((unsigned)y1[k]) << 16), acc[k]);
        }
    }
    // reduce across the 2 edge slots (bit 3 — stays within the quarter)
#pragma unroll
    for (int k = 0; k < 8; k++)
        acc[k] += __shfl_xor(acc[k], 8);
    if (active && sub == 0) {
        float dr = dis[row];
        float4 b0 = ((const float4*)bias)[f8 * 2];
        float4 b1 = ((const float4*)bias)[f8 * 2 + 1];
        float4 o0, o1;
        o0.x = fmaxf(fmaf(dr, acc[0], b0.x), 0.f);
        o0.y = fmaxf(fmaf(dr, acc[1], b0.y), 0.f);
        o0.z = fmaxf(fmaf(dr, acc[2], b0.z), 0.f);
        o0.w = fmaxf(fmaf(dr, acc[3], b0.w), 0.f);
        o1.x = fmaxf(fmaf(dr, acc[4], b1.x), 0.f);
        o1.y = fmaxf(fmaf(dr, acc[5], b1.y), 0.f);
        o1.z = fmaxf(fmaf(dr, acc[6], b1.z), 0.f);
        o1.w = fmaxf(fmaf(dr, acc[7], b1.w), 0.f);
        float4* op = (float4*)(out + (size_t)row * DFEAT + f8 * 8);
        op[0] = o0;
        op[1] = o1;
    }
}

// ---------------------------------------------------------------------------
extern "C" void kernel_launch(void* const* d_in, const int* in_sizes, int n_in,
                              void* d_out, int out_size, void* d_ws, size_t ws_size,
                              hipStream_t stream) {
    const float* feat = (const float*)d_in[0];   // [N, 64] f32
    const int*   ei   = (const int*)d_in[1];     // [2, E] int32 (rows then cols)
    const float* W    = (const float*)d_in[2];   // [64, 64] f32
    const float* bias = (const float*)d_in[3];   // [64] f32
    float* out = (float*)d_out;                  // [N, 64] f32

    int n = in_sizes[0] / DFEAT;                 // 100000
    int E = in_sizes[1] / 2;                     // 1250000
    int nSB = (n + SBROWS - 1) >> SBSHIFT;       // 196

    // workspace layout (int units; every region 16B-aligned):
    int* ws = (int*)d_ws;
    size_t o = 0;
    int*   sbcursor = ws + o; o += 256 * CURPAD; // padded: 1 counter / 64B line
    float* dis      = (float*)(ws + o); o += (size_t)n;
    int*   row_beg  = ws + o; o += (size_t)n;
    int*   row_end  = ws + o; o += (size_t)n;
    int*   packed   = ws + o; o += (size_t)nSB << CAPSHIFT;
    int*   csr_col  = ws + o; o += (size_t)nSB << CAPSHIFT;
    ushort8* Y      = (ushort8*)(ws + o);        // n * 64 bf16 = n*16 ints

    hipMemsetAsync(sbcursor, 0, 256 * CURPAD * sizeof(int), stream);

    int binABlocks = (E + CHUNK - 1) / CHUNK;    // 611
    int xwBlocks = (n + 63) / 64;                // 1563 (64 rows/block, MFMA)
    binA_xw_kernel<<<binABlocks + xwBlocks, 256, 0, stream>>>(
        feat, W, (unsigned short*)Y, n, ei, E, sbcursor, packed, binABlocks);
    binB_kernel<<<nSB, 256, 0, stream>>>(sbcursor, packed, csr_col, row_beg, row_end, dis, n);
    spmm_kernel<<<((n + 3) / 4 + 3) / 4, 256, 0, stream>>>(
        row_beg, row_end, csr_col, dis, Y, bias, out, n);
}

// Round 14
// 143.897 us; speedup vs baseline: 1.0536x; 1.0536x over previous
//
#include <hip/hip_runtime.h>
#include <hip/hip_bf16.h>

#define DFEAT 64
#define SBSHIFT 9            // 512 rows per superbucket
#define SBROWS 512
#define CAPSHIFT 13          // 8192 edge slots per superbucket region
#define CAP 8192
#define CHUNK 4096           // R27: back to measured-optimum (2048/8192 both regress)
#define RPT 16               // CHUNK/256
#define CURPAD 16            // sbcursor padded: one counter per 64B line

typedef __attribute__((ext_vector_type(8))) unsigned short ushort8;
typedef __attribute__((ext_vector_type(8))) short short8;    // MFMA A/B frag (8 bf16)
typedef __attribute__((ext_vector_type(4))) float f32x4;     // MFMA C/D frag

static __device__ __forceinline__ unsigned short f2bf(float f) {
    __hip_bfloat16 h = __float2bfloat16(f);   // RNE
    unsigned short u;
    __builtin_memcpy(&u, &h, 2);
    return u;
}

// ---------------------------------------------------------------------------
// R27: col-prefetch in binA. CHUNK sweep closed (2048:151.6 / 4096:146.7 /
// 8192:151.5 — 4096 optimal). R24's counters (Occ 13%, VALU 5%, HBM 11%)
// show binA blocks are the long pole: pass-3's serial chain
// {load ei[E+idx] ~200-900cy -> LDS atomic -> scatter} x16. Cols are
// independent of the chain => prefetch cv[k] during pass 1 (coalesced,
// hidden under histogram). Pass 3 becomes LDS-atomic + store only; ei cols
// read once instead of twice. Same values/race semantics => bit-identical.
// [R20: MFMA xw kept. R17: spmm x2 unroll kept. R21/R23 rowmap closed.
//  R15/R16: no grid-barrier fusion on MI355X.]
// ---------------------------------------------------------------------------

// ---------------------------------------------------------------------------
// 1) FUSED: binA (blocks [0,binABlocks)) || xw-MFMA (64 rows/block).
//    LDS: binA 2 KB (hist+cur); xw uses none.
// ---------------------------------------------------------------------------
__global__ __launch_bounds__(256) void binA_xw_kernel(
        const float* __restrict__ feat, const float* __restrict__ W,
        unsigned short* __restrict__ Yu, int n,
        const int* __restrict__ ei, int E,
        int* __restrict__ sbcursor, int* __restrict__ packed, int binABlocks) {
    __shared__ int hist[256];
    __shared__ int cur[256];

    if (blockIdx.x < binABlocks) {
        // ---------------- binA part ----------------
        int t = threadIdx.x;
        hist[t] = 0;
        __syncthreads();

        int base = blockIdx.x * CHUNK;
        int rv[RPT];
        int cv[RPT];
#pragma unroll
        for (int k = 0; k < RPT; k++) {
            int idx = base + k * 256 + t;
            bool ok = (idx < E);
            rv[k] = ok ? ei[idx] : -1;
            cv[k] = ok ? ei[E + idx] : 0;       // prefetched col (R27)
            if (ok) atomicAdd(&hist[rv[k] >> SBSHIFT], 1);
        }
        __syncthreads();

        int h = hist[t];
        cur[t] = (h > 0) ? atomicAdd(&sbcursor[t * CURPAD], h) : 0;  // absolute base
        __syncthreads();

#pragma unroll
        for (int k = 0; k < RPT; k++) {
            if (rv[k] >= 0) {
                int r = rv[k];
                int sb = r >> SBSHIFT;
                int pos = atomicAdd(&cur[sb], 1);
                if (pos < CAP)
                    packed[(sb << CAPSHIFT) + pos] =
                        ((r & (SBROWS - 1)) << 17) | cv[k];
            }
        }
    } else {
        // ---------------- xw part: MFMA, 16 rows/wave, 64 rows/block -------
        int bid  = blockIdx.x - binABlocks;
        int wave = threadIdx.x >> 6;
        int lane = threadIdx.x & 63;
        int lr = lane & 15;           // A-row / B-col / C-col within tile
        int lg = lane >> 4;           // k-group (A,B) / row-group (C)
        int R0 = bid * 64 + wave * 16;

        // B fragments: W[64][64] row-major; b[nb][ks][j] = W[ks*32+lg*8+j][nb*16+lr]
        short8 bf[4][2];
#pragma unroll
        for (int nb = 0; nb < 4; nb++) {
#pragma unroll
            for (int ks = 0; ks < 2; ks++) {
#pragma unroll
                for (int j = 0; j < 8; j++) {
                    int k = ks * 32 + lg * 8 + j;
                    bf[nb][ks][j] = (short)f2bf(W[k * DFEAT + nb * 16 + lr]);
                }
            }
        }

        // A fragments: a[ks][j] = feat[R0+lr][ks*32+lg*8+j]
        short8 af[2];
        int arow = R0 + lr;
        if (arow < n) {
            const float4* ap =
                (const float4*)(feat + (size_t)arow * DFEAT + lg * 8);
            float4 f0 = ap[0];            // k = lg*8 .. +3      (ks=0)
            float4 f1 = ap[1];            // k = lg*8+4 .. +7    (ks=0)
            float4 f2 = ap[8];            // +32 floats = 8 float4 (ks=1)
            float4 f3 = ap[9];
            af[0][0] = (short)f2bf(f0.x); af[0][1] = (short)f2bf(f0.y);
            af[0][2] = (short)f2bf(f0.z); af[0][3] = (short)f2bf(f0.w);
            af[0][4] = (short)f2bf(f1.x); af[0][5] = (short)f2bf(f1.y);
            af[0][6] = (short)f2bf(f1.z); af[0][7] = (short)f2bf(f1.w);
            af[1][0] = (short)f2bf(f2.x); af[1][1] = (short)f2bf(f2.y);
            af[1][2] = (short)f2bf(f2.z); af[1][3] = (short)f2bf(f2.w);
            af[1][4] = (short)f2bf(f3.x); af[1][5] = (short)f2bf(f3.y);
            af[1][6] = (short)f2bf(f3.z); af[1][7] = (short)f2bf(f3.w);
        } else {
#pragma unroll
            for (int j = 0; j < 8; j++) { af[0][j] = 0; af[1][j] = 0; }
        }

        // C[16x16] per N-tile: accumulate the two K-steps
        f32x4 c[4];
#pragma unroll
        for (int nb = 0; nb < 4; nb++) {
            c[nb] = (f32x4){0.f, 0.f, 0.f, 0.f};
            c[nb] = __builtin_amdgcn_mfma_f32_16x16x32_bf16(af[0], bf[nb][0],
                                                            c[nb], 0, 0, 0);
            c[nb] = __builtin_amdgcn_mfma_f32_16x16x32_bf16(af[1], bf[nb][1],
                                                            c[nb], 0, 0, 0);
        }

        // store: c[nb][i] -> Y[R0 + lg*4 + i][nb*16 + lr] (bf16)
#pragma unroll
        for (int i = 0; i < 4; i++) {
            int row = R0 + lg * 4 + i;
            if (row < n) {
#pragma unroll
                for (int nb = 0; nb < 4; nb++)
                    Yu[(size_t)row * DFEAT + nb * 16 + lr] = f2bf(c[nb][i]);
            }
        }
    }
}

// ---------------------------------------------------------------------------
// 2) binB: per-superbucket counting sort into CSR order (block-private dense
//    region, native int LDS atomics only). Emits row_beg/row_end/dis.
// ---------------------------------------------------------------------------
__global__ void binB_kernel(const int* __restrict__ sbcursor, const int* __restrict__ packed,
                            int* __restrict__ csr_col, int* __restrict__ row_beg,
                            int* __restrict__ row_end, float* __restrict__ dis, int n) {
    __shared__ int rcnt[SBROWS];
    __shared__ int rcur[SBROWS];
    int sb = blockIdx.x;
    int t = threadIdx.x;
    int cnt = min(sbcursor[sb * CURPAD], CAP);
    const int* pk = packed + ((size_t)sb << CAPSHIFT);
    for (int i = t; i < SBROWS; i += 256) rcnt[i] = 0;
    __syncthreads();
    for (int i = t; i < cnt; i += 256) atomicAdd(&rcnt[pk[i] >> 17], 1);
    __syncthreads();
    // exclusive scan of rcnt[512] by wave 0 (8 elems/lane + shfl_up scan)
    if (t < 64) {
        int v[8];
        int run = 0;
#pragma unroll
        for (int k = 0; k < 8; k++) { v[k] = run; run += rcnt[t * 8 + k]; }
        int x = run;
        for (int off = 1; off < 64; off <<= 1) {
            int y = __shfl_up(x, off);
            if (t >= off) x += y;
        }
        int excl = x - run;
#pragma unroll
        for (int k = 0; k < 8; k++) rcur[t * 8 + k] = excl + v[k];
    }
    __syncthreads();
    int rows = min(SBROWS, n - sb * SBROWS);
    for (int rl = t; rl < rows; rl += 256) {
        int beg = (sb << CAPSHIFT) + rcur[rl];
        int d = rcnt[rl];
        int r = sb * SBROWS + rl;
        row_beg[r] = beg;
        row_end[r] = beg + d;
        dis[r] = (d > 0) ? rsqrtf((float)d) : 0.0f;
    }
    __syncthreads();
    for (int i = t; i < cnt; i += 256) {
        int p = pk[i];
        int pos = atomicAdd(&rcur[p >> 17], 1);
        csr_col[(sb << CAPSHIFT) + pos] = p & 0x1FFFF;
    }
}

// ---------------------------------------------------------------------------
// 3) spmm: FOUR rows per wave (one per 16-lane quarter). Quarter layout:
//    2 edge slots (sub) x 8 feat chunks (f8, 16 B bf16 loads). Guard-free
//    inner loop (tail slots shfl from lanes holding c=0/dv=0 -> Y[0]
//    broadcast gather, fma adds 0). x2 unroll (R17 measured-best; x4 was
//    neutral). Register accumulate, quarter-local shfl_xor reduce, fused
//    dis/bias/relu epilogue. Zero atomics.
// ---------------------------------------------------------------------------
__global__ __launch_bounds__(256) void spmm_kernel(
        const int* __restrict__ row_beg, const int* __restrict__ row_end,
        const int* __restrict__ csr_col, const float* __restrict__ dis,
        const ushort8* __restrict__ Y, const float* __restrict__ bias,
        float* __restrict__ out, int n) {
    int wid = (int)(((long long)blockIdx.x * blockDim.x + threadIdx.x) >> 6);
    int lane = threadIdx.x & 63;
    int h = lane >> 4;            // which of the wave's four rows (0..3)
    int lq = lane & 15;           // lane within quarter
    int qb = h << 4;              // quarter base lane
    int row = wid * 4 + h;
    bool active = row < n;
    int s = active ? row_beg[row] : 0;
    int e = active ? row_end[row] : 0;
    int sub = lq >> 3;            // edge slot 0..1
    int f8 = lane & 7;            // feat chunk 0..7
    float acc[8] = {0.f, 0.f, 0.f, 0.f, 0.f, 0.f, 0.f, 0.f};
    for (int base = s; base < e; base += 16) {
        int cnt = min(16, e - base);
        int c = 0;
        float dv = 0.f;
        if (lq < cnt) { c = csr_col[base + lq]; dv = dis[c]; }
        for (int i = 0; i < cnt; i += 4) {
            int   ce0 = __shfl(c,  qb + i + sub);      // tail slot -> c=0
            float de0 = __shfl(dv, qb + i + sub);      // -> 0.0f
            int   ce1 = __shfl(c,  qb + i + 2 + sub);
            float de1 = __shfl(dv, qb + i + 2 + sub);
            ushort8 y0 = Y[(size_t)ce0 * 8 + f8];      // two gathers in flight
            ushort8 y1 = Y[(size_t)ce1 * 8 + f8];
#pragma unroll
            for (int k = 0; k < 8; k++)
                acc[k] = fmaf(de0, __uint_as_float(((unsigned)y0[k]) << 16), acc[k]);
#pragma unroll
            for (int k = 0; k < 8; k++)
                acc[k] = fmaf(de1, __uint_as_float(((unsigned)y1[k]) << 16), acc[k]);
        }
    }
    // reduce across the 2 edge slots (bit 3 — stays within the quarter)
#pragma unroll
    for (int k = 0; k < 8; k++)
        acc[k] += __shfl_xor(acc[k], 8);
    if (active && sub == 0) {
        float dr = dis[row];
        float4 b0 = ((const float4*)bias)[f8 * 2];
        float4 b1 = ((const float4*)bias)[f8 * 2 + 1];
        float4 o0, o1;
        o0.x = fmaxf(fmaf(dr, acc[0], b0.x), 0.f);
        o0.y = fmaxf(fmaf(dr, acc[1], b0.y), 0.f);
        o0.z = fmaxf(fmaf(dr, acc[2], b0.z), 0.f);
        o0.w = fmaxf(fmaf(dr, acc[3], b0.w), 0.f);
        o1.x = fmaxf(fmaf(dr, acc[4], b1.x), 0.f);
        o1.y = fmaxf(fmaf(dr, acc[5], b1.y), 0.f);
        o1.z = fmaxf(fmaf(dr, acc[6], b1.z), 0.f);
        o1.w = fmaxf(fmaf(dr, acc[7], b1.w), 0.f);
        float4* op = (float4*)(out + (size_t)row * DFEAT + f8 * 8);
        op[0] = o0;
        op[1] = o1;
    }
}

// ---------------------------------------------------------------------------
extern "C" void kernel_launch(void* const* d_in, const int* in_sizes, int n_in,
                              void* d_out, int out_size, void* d_ws, size_t ws_size,
                              hipStream_t stream) {
    const float* feat = (const float*)d_in[0];   // [N, 64] f32
    const int*   ei   = (const int*)d_in[1];     // [2, E] int32 (rows then cols)
    const float* W    = (const float*)d_in[2];   // [64, 64] f32
    const float* bias = (const float*)d_in[3];   // [64] f32
    float* out = (float*)d_out;                  // [N, 64] f32

    int n = in_sizes[0] / DFEAT;                 // 100000
    int E = in_sizes[1] / 2;                     // 1250000
    int nSB = (n + SBROWS - 1) >> SBSHIFT;       // 196

    // workspace layout (int units; every region 16B-aligned):
    int* ws = (int*)d_ws;
    size_t o = 0;
    int*   sbcursor = ws + o; o += 256 * CURPAD; // padded: 1 counter / 64B line
    float* dis      = (float*)(ws + o); o += (size_t)n;
    int*   row_beg  = ws + o; o += (size_t)n;
    int*   row_end  = ws + o; o += (size_t)n;
    int*   packed   = ws + o; o += (size_t)nSB << CAPSHIFT;
    int*   csr_col  = ws + o; o += (size_t)nSB << CAPSHIFT;
    ushort8* Y      = (ushort8*)(ws + o);        // n * 64 bf16 = n*16 ints

    hipMemsetAsync(sbcursor, 0, 256 * CURPAD * sizeof(int), stream);

    int binABlocks = (E + CHUNK - 1) / CHUNK;    // 306
    int xwBlocks = (n + 63) / 64;                // 1563 (64 rows/block, MFMA)
    binA_xw_kernel<<<binABlocks + xwBlocks, 256, 0, stream>>>(
        feat, W, (unsigned short*)Y, n, ei, E, sbcursor, packed, binABlocks);
    binB_kernel<<<nSB, 256, 0, stream>>>(sbcursor, packed, csr_col, row_beg, row_end, dis, n);
    spmm_kernel<<<((n + 3) / 4 + 3) / 4, 256, 0, stream>>>(
        row_beg, row_end, csr_col, dis, Y, bias, out, n);
}